// Round 25
// baseline (269.865 us; speedup 1.0000x reference)
//
#include <hip/hip_runtime.h>
#include <hip/hip_fp16.h>
#include <cstddef>

typedef _Float16 f16;
typedef __attribute__((ext_vector_type(8))) _Float16 f16x8;
typedef __attribute__((ext_vector_type(4))) _Float16 f16x4;
typedef __attribute__((ext_vector_type(2))) _Float16 f16x2;
typedef __attribute__((ext_vector_type(4))) float f32x4;
typedef __attribute__((ext_vector_type(16))) float f32x16;
typedef __attribute__((ext_vector_type(4))) unsigned int u32x4;
typedef unsigned int u32;

#define LOG2E 1.44269504088896340736f

typedef __attribute__((address_space(1))) const unsigned int gau32;
typedef __attribute__((address_space(3))) unsigned int lau32;

// ---------------- workspace layout (bytes) ----------------
#define OFF_NORM  0ull                                // 2 floats (sumsq q, sumsq k)
#define OFF_SLOTS 128ull                              // 64 slot-pairs (spread atomics), 512 B
#define OFF_WT    1024ull                             // f16 wt2[12ct][8ks][32ln][2hi][8] (wave-coalesced)
#define OFF_PWT   (OFF_WT + 384ull*128*2)             // f16 pwt2[4ct][8ks][32ln][2hi][8] (wave-coalesced)
#define OFF_BIASP (OFF_PWT + 128ull*128*2)            // f16 bias2[4h][8g][8mt][32ln][2hi][16] (xLOG2E)
#define OFF_MASKP (OFF_BIASP + 4ull*256*256*2)        // f16 mask2[64w][8g][8mt][32ln][2hi][16] (xLOG2E)
#define OFF_QKV   (OFF_MASKP + 64ull*256*256*2)       // f16 q[1024][4][256][32] (-> overwritten by O), k same, vT[1024][4][32][256]
// end = OFF_QKV + 201,326,592 = 210,371,584 bytes (proven size)

#define QSZ 33554432ull   // elements per q/k/v section

// ---------------- K1: rel-pos bias MLP -> wave-coalesced f16 table (log2e-scaled) ----------------
__global__ void k_bias(const float* __restrict__ rel, const float* __restrict__ fc1w,
                       const float* __restrict__ fc1b, const float* __restrict__ fc2w,
                       const float* __restrict__ fc2b, f16* __restrict__ biasp) {
  int n = blockIdx.x, m = threadIdx.x;
  float r0 = rel[(n*256 + m)*2 + 0];
  float r1 = rel[(n*256 + m)*2 + 1];
  float a0 = fc2b[0], a1 = fc2b[1], a2 = fc2b[2], a3 = fc2b[3];
  for (int i = 0; i < 128; ++i) {
    float h = fmaf(r0, fc1w[i], fmaf(r1, fc1w[128 + i], fc1b[i]));
    float t = tanhf(0.7978845608028654f * (h + 0.044715f * h * h * h));
    float g = 0.5f * h * (1.0f + t);
    a0 = fmaf(g, fc2w[i*4 + 0], a0);
    a1 = fmaf(g, fc2w[i*4 + 1], a1);
    a2 = fmaf(g, fc2w[i*4 + 2], a2);
    a3 = fmaf(g, fc2w[i*4 + 3], a3);
  }
  int g = n >> 5, ln = n & 31;
  int mt = m >> 5, rem = m & 31;
  int rq = rem >> 3, hi = (rem >> 2) & 1, i = rem & 3;
  size_t base = (((size_t)(g*8 + mt)*32 + ln)*2 + hi)*16 + (rq*4 + i);
  biasp[0*65536 + base] = (f16)(a0 * LOG2E);
  biasp[1*65536 + base] = (f16)(a1 * LOG2E);
  biasp[2*65536 + base] = (f16)(a2 * LOG2E);
  biasp[3*65536 + base] = (f16)(a3 * LOG2E);
}

// ---------------- K2: weight transposes (fp32 -> fp16, both wave-coalesced) ----------------
__global__ void k_transpose(const float* __restrict__ qkvw, const float* __restrict__ projw,
                            f16* __restrict__ wt, f16* __restrict__ pwt) {
  int idx = blockIdx.x*256 + threadIdx.x;        // 0..65535
  if (idx < 49152) {
    int col = idx >> 7, k = idx & 127;
    int ct = col >> 5, ln = col & 31;
    int ks = k >> 4, hi = (k >> 3) & 1, j = k & 7;
    wt[(((size_t)(ct*8 + ks)*32 + ln)*2 + hi)*8 + j] = (f16)qkvw[k*384 + col];
  } else {
    int p = idx - 49152;
    int col = p >> 7, k = p & 127;
    int ct = col >> 5, ln = col & 31;
    int ks = k >> 4, hi = (k >> 3) & 1, j = k & 7;
    pwt[(((size_t)(ct*8 + ks)*32 + ln)*2 + hi)*8 + j] = (f16)projw[k*128 + col];
  }
}

// ---------------- K3: mask fp32 -> wave-coalesced f16 (log2e-scaled) ----------------
__global__ void k_perm(const float* __restrict__ mask, f16* __restrict__ maskp) {
  int t = blockIdx.x*256 + threadIdx.x;          // 0..262143
  int mt = t & 7, hi = (t >> 3) & 1, n = (t >> 4) & 255, w = t >> 12;
  int g = n >> 5, ln = n & 31;
  const float* src = mask + (size_t)(w*256 + n)*256;
  f16* dst = maskp + (size_t)w*65536 + (((size_t)(g*8 + mt)*32 + ln)*2 + hi)*16;
  #pragma unroll
  for (int rq = 0; rq < 4; ++rq) {
    f32x4 v = *(const f32x4*)(src + mt*32 + rq*8 + hi*4);
    #pragma unroll
    for (int i = 0; i < 4; ++i) dst[rq*4 + i] = (f16)(v[i] * LOG2E);
  }
}

// ---------------- K4: QKV GEMM (unchanged from r21) ----------------
__global__ __launch_bounds__(512, 6)
void k_qkv(const float* __restrict__ x, const f16* __restrict__ wt,
           const float* __restrict__ qkvb, f16* __restrict__ qkv,
           float* __restrict__ slots) {
  __shared__ f16 xs[8192];
  int tid = threadIdx.x;
  int wv = tid >> 6, lane = tid & 63;
  int ln = lane & 31, hi = lane >> 5;

  {
    const float* xt = x + (size_t)blockIdx.x*8192;
    char* xw = (char*)xs;
    #pragma unroll
    for (int it = 0; it < 4; ++it) {
      int idx = it*2048 + tid*4;
      int rowl = idx >> 7, col = idx & 127;
      f32x4 v = *(const f32x4*)(xt + idx);
      f16x4 hv;
      #pragma unroll
      for (int j = 0; j < 4; ++j) hv[j] = (f16)v[j];
      *(f16x4*)(xw + rowl*256 + ((col*2) ^ ((rowl & 15) << 4))) = hv;
    }
  }
  __syncthreads();

  int rl = (wv >> 2)*32 + ln;
  int row = blockIdx.x*64 + rl;
  int b_ = row >> 8, n = row & 255;
  int ct0 = (wv & 3)*3;

  f16x8 xf[8];
  {
    const char* xw = (const char*)xs;
    #pragma unroll
    for (int ks = 0; ks < 8; ++ks)
      xf[ks] = *(const f16x8*)(xw + rl*256 + ((ks*32 + hi*16) ^ ((rl & 15) << 4)));
  }
  __syncthreads();

  char* tb = (char*)xs + wv*2048;
  int nb0 = blockIdx.x*64 + (wv >> 2)*32;
  int b2 = nb0 >> 8, n2 = nb0 & 255;

  float sq = 0.f, sk = 0.f;
  #pragma unroll 1
  for (int cc = 0; cc < 3; ++cc) {
    int ct = ct0 + cc;
    f32x16 acc;
    #pragma unroll
    for (int g = 0; g < 4; ++g) {
      f32x4 qb = *(const f32x4*)(qkvb + ct*32 + g*8 + hi*4);
      #pragma unroll
      for (int i = 0; i < 4; ++i) acc[g*4 + i] = qb[i];
    }
    const f16* wbase = wt + (size_t)(ct*8)*512 + (ln*2 + hi)*8;
    #pragma unroll
    for (int ks = 0; ks < 8; ++ks) {
      f16x8 wf = *(const f16x8*)(wbase + ks*512);
      acc = __builtin_amdgcn_mfma_f32_32x32x16_f16(wf, xf[ks], acc, 0, 0, 0);
    }
    int which = ct >> 2, hh = ct & 3;
    if (which == 0) {
      #pragma unroll
      for (int r = 0; r < 16; ++r) sq = fmaf(acc[r], acc[r], sq);
    } else if (which == 1) {
      #pragma unroll
      for (int r = 0; r < 16; ++r) sk = fmaf(acc[r], acc[r], sk);
    }
    if (which < 2) {
      #pragma unroll
      for (int g = 0; g < 4; ++g) {
        f16x4 pk;
        #pragma unroll
        for (int i = 0; i < 4; ++i) pk[i] = (f16)acc[g*4 + i];
        *(f16x4*)(tb + g*512 + ln*16 + hi*8) = pk;
      }
      f16* dst0 = qkv + (size_t)which*QSZ + ((size_t)(b2*4 + hh)*256 + n2)*32;
      #pragma unroll
      for (int it = 0; it < 2; ++it) {
        int r = it*16 + (lane >> 2), u = lane & 3;
        f16x8 vv = *(const f16x8*)(tb + u*512 + r*16);
        *(f16x8*)((char*)dst0 + it*1024 + lane*16) = vv;
      }
    } else {
      f16* dst = qkv + 2ull*QSZ + ((size_t)(b_*4 + hh)*32)*256 + n;
      #pragma unroll
      for (int g = 0; g < 4; ++g) {
        #pragma unroll
        for (int i = 0; i < 4; ++i) {
          int dd = g*8 + hi*4 + i;
          dst[(size_t)dd*256] = (f16)acc[g*4 + i];
        }
      }
    }
  }
  #pragma unroll
  for (int o = 32; o > 0; o >>= 1) { sq += __shfl_xor(sq, o); sk += __shfl_xor(sk, o); }
  __syncthreads();
  float* red = (float*)xs;
  if (lane == 0) { red[wv*2] = sq; red[wv*2 + 1] = sk; }
  __syncthreads();
  if (tid == 0) {
    float a = 0.f, bsum = 0.f;
    #pragma unroll
    for (int i = 0; i < 8; ++i) { a += red[i*2]; bsum += red[i*2 + 1]; }
    float* sl = slots + 2*(blockIdx.x & 63);
    atomicAdd(sl + 0, a);
    atomicAdd(sl + 1, bsum);
  }
}

// ---------------- K4b: reduce 64 slot-pairs -> norms ----------------
__global__ void k_norm(const float* __restrict__ slots, float* __restrict__ norms) {
  int l = threadIdx.x;
  float a = slots[2*l], b = slots[2*l + 1];
  #pragma unroll
  for (int o = 32; o > 0; o >>= 1) { a += __shfl_xor(a, o); b += __shfl_xor(b, o); }
  if (l == 0) { norms[0] = a; norms[1] = b; }
}

// ---------------- K5: window attention, 2-stage software-pipelined mt loop (T15) ----------------
// Stage A computes softmax+PV of tile cA while stage B's QK MFMAs for the next tile issue.
// Named cA/cB via hand-unrolled x2 loop (no runtime-indexed register arrays).
#define QKTILE(DST, MT) { \
  f16x8 ka0 = *(const f16x8*)(kbuf + ((size_t)(((MT)*4 + hi)*32 + ln))*8); \
  f16x8 ka1 = *(const f16x8*)(kbuf + ((size_t)(((MT)*4 + 2 + hi)*32 + ln))*8); \
  f32x16 z_; \
  _Pragma("unroll") for (int r_ = 0; r_ < 16; ++r_) z_[r_] = 0.f; \
  DST = __builtin_amdgcn_mfma_f32_32x32x16_f16(ka0, qf0, z_, 0, 0, 0); \
  DST = __builtin_amdgcn_mfma_f32_32x32x16_f16(ka1, qf1, DST, 0, 0, 0); \
}

#define SMPV(C, MT) { \
  u32 u[8]; \
  const u32* bpj = bp0 + (MT)*512; \
  const u32* mpj = mp0 + (MT)*512; \
  _Pragma("unroll") for (int j = 0; j < 8; ++j) { \
    f16x2 bm = __builtin_bit_cast(f16x2, bpj[j]) + __builtin_bit_cast(f16x2, mpj[j]); \
    f16x2 cp = __builtin_bit_cast(f16x2, __builtin_amdgcn_cvt_pkrtz(C[2*j], C[2*j + 1])); \
    f16x2 l2 = cp * s2 + bm; \
    __half2 e = h2exp2(__builtin_bit_cast(__half2, l2)); \
    u[j] = __builtin_bit_cast(u32, e); \
  } \
  _Pragma("unroll") for (int half = 0; half < 2; ++half) { \
    u32 q0 = u[half*4 + 0], q1 = u[half*4 + 1], q2 = u[half*4 + 2], q3 = u[half*4 + 3]; \
    asm volatile("v_permlane32_swap_b32 %0, %1" : "+v"(q0), "+v"(q2)); \
    asm volatile("v_permlane32_swap_b32 %0, %1" : "+v"(q1), "+v"(q3)); \
    u32x4 av; av[0] = q0; av[1] = q1; av[2] = q2; av[3] = q3; \
    f16x8 afrag = __builtin_bit_cast(f16x8, av); \
    int ks = (MT)*2 + half; \
    f16x8 vfrag = *(const f16x8*)(vbuf + ((size_t)((2*ks + hi)*32 + ln))*8); \
    oacc = __builtin_amdgcn_mfma_f32_32x32x16_f16(afrag, vfrag, oacc, 0, 0, 0); \
    sacc = __builtin_amdgcn_mfma_f32_32x32x16_f16(afrag, ones, sacc, 0, 0, 0); \
  } \
}

__global__ __launch_bounds__(512, 4)
void k_attn(const f16* __restrict__ qkv, f16* __restrict__ qo,
            const f16* __restrict__ biasp, const f16* __restrict__ maskp,
            const float* __restrict__ norms, const float* __restrict__ taup) {
  __shared__ f16 kbuf[8192];
  __shared__ f16 vbuf[8192];

  int blk = blockIdx.x;
  int xcd = blk & 7, s = blk >> 3;
  int b = (s >> 2)*8 + xcd;
  int h = s & 3;
  int w = b & 63;
  int tid = threadIdx.x;
  int wv = tid >> 6, lane = tid & 63;
  int ln = lane & 31, hi = lane >> 5;
  int n0 = wv * 32;
  int nrow = n0 + ln;

  float tau = fmaxf(taup[0], 0.01f);
  float scale = LOG2E / (sqrtf(norms[0]) * sqrtf(norms[1]) * tau);
  f16 scale_h = (f16)scale;
  f16x2 s2 = {scale_h, scale_h};

  const f16* qrow = qkv + (size_t)(b*4 + h)*8192 + (size_t)nrow*32 + hi*8;
  f16x8 qf0 = *(const f16x8*)(qrow);
  f16x8 qf1 = *(const f16x8*)(qrow + 16);

  {
    const char* kg = (const char*)(qkv + QSZ + (size_t)(b*4 + h)*8192);
    const char* vg = (const char*)(qkv + 2ull*QSZ + (size_t)(b*4 + h)*8192);
    #pragma unroll
    for (int it = 0; it < 2; ++it) {
      int t = it*512 + wv*64 + lane;
      int mt_ = t >> 7, ch = (t >> 5) & 3, l = t & 31;
      const char* src = kg + ((mt_*32 + l)*64 + ch*16);
      char* dst = (char*)kbuf + (size_t)(it*512 + wv*64)*16;
      __builtin_amdgcn_global_load_lds((gau32*)src, (lau32*)dst, 16, 0, 0);
    }
    #pragma unroll
    for (int it = 0; it < 2; ++it) {
      int t = it*512 + wv*64 + lane;
      int kc = t >> 5, dd = t & 31;
      const char* src = vg + (dd*512 + kc*16);
      char* dst = (char*)vbuf + (size_t)(it*512 + wv*64)*16;
      __builtin_amdgcn_global_load_lds((gau32*)src, (lau32*)dst, 16, 0, 0);
    }
  }
  __syncthreads();

  int g = wv;
  const u32* bp0 = (const u32*)biasp + (size_t)(h*8 + g)*4096 + (ln*2 + hi)*8;
  const u32* mp0 = (const u32*)maskp + (size_t)w*32768 + (size_t)g*4096 + (ln*2 + hi)*8;

  f32x16 oacc, sacc;
  #pragma unroll
  for (int r = 0; r < 16; ++r) { oacc[r] = 0.f; sacc[r] = 0.f; }
  f16x8 ones;
  #pragma unroll
  for (int j = 0; j < 8; ++j) ones[j] = (f16)1.0f;

  // 2-stage pipeline: QK(mt+1) issues before softmax+PV(mt) consumes cA/cB.
  f32x16 cA, cB;
  QKTILE(cA, 0);
  #pragma unroll 1
  for (int it2 = 0; it2 < 4; ++it2) {
    int mtA = it2*2, mtB = it2*2 + 1;
    QKTILE(cB, mtB);        // MFMA pipe fills while...
    SMPV(cA, mtA);          // ...VALU runs softmax(A), then PV(A) MFMAs
    if (it2 < 3) QKTILE(cA, mtB + 1);
    SMPV(cB, mtB);
  }

  f16* ob = qo + (size_t)(b*4 + h)*8192 + (size_t)n0*32 + ln;
  #pragma unroll
  for (int r = 0; r < 16; ++r) {
    int nl = (r & 3) + 8*(r >> 2) + 4*hi;
    float rcp = __builtin_amdgcn_rcpf(sacc[r]);
    ob[nl*32] = (f16)(oacc[r] * rcp);
  }
}
#undef QKTILE
#undef SMPV

// ---------------- K6: proj GEMM with LDS-staged O (unchanged from r24) ----------------
__global__ __launch_bounds__(256, 4)
void k_proj(const f16* __restrict__ O, const f16* __restrict__ pwt,
            const float* __restrict__ projb, float* __restrict__ out) {
  __shared__ f16 os[16384];
  int blk = blockIdx.x;
  int xcd = blk & 7, s = blk >> 3;
  int window = (s >> 1)*8 + xcd;
  int half = s & 1;
  int tid = threadIdx.x;
  int wv = tid >> 6, lane = tid & 63;
  int ln = lane & 31, hi = lane >> 5;

  {
    const char* obase = (const char*)(O + ((size_t)window*4*256 + half*128)*32);
    char* ow = (char*)os;
    #pragma unroll
    for (int it = 0; it < 8; ++it) {
      int flat = it*4096 + tid*16;
      int h = flat >> 13;
      int rem = flat & 8191;
      int nloc = rem >> 6;
      int db = rem & 63;
      f16x8 v = *(const f16x8*)(obase + (size_t)h*16384 + nloc*64 + db);
      int cb = h*64 + db;
      *(f16x8*)(ow + nloc*256 + (cb ^ ((nloc & 15) << 4))) = v;
    }
  }
  __syncthreads();

  int rl = wv*32 + ln;
  int row0 = window*256 + half*128 + wv*32;

  f16x8 afr[8];
  {
    const char* ow = (const char*)os;
    #pragma unroll
    for (int ks = 0; ks < 8; ++ks)
      afr[ks] = *(const f16x8*)(ow + rl*256 + ((ks*32 + hi*16) ^ ((rl & 15) << 4)));
  }

  #pragma unroll 1
  for (int ct = 0; ct < 4; ++ct) {
    int cout = ct*32 + ln;
    float pb = projb[cout];
    f32x16 pacc;
    #pragma unroll
    for (int r = 0; r < 16; ++r) pacc[r] = pb;
    const f16* pbase = pwt + (size_t)(ct*8)*512 + (ln*2 + hi)*8;
    #pragma unroll
    for (int ks = 0; ks < 8; ++ks) {
      f16x8 bfr = *(const f16x8*)(pbase + ks*512);
      pacc = __builtin_amdgcn_mfma_f32_32x32x16_f16(afr[ks], bfr, pacc, 0, 0, 0);
    }
    #pragma unroll
    for (int r = 0; r < 16; ++r) {
      int nl = (r & 3) + 8*(r >> 2) + 4*hi;
      out[(size_t)(row0 + nl)*128 + cout] = pacc[r];
    }
  }
}

// ---------------- launch ----------------
extern "C" void kernel_launch(void* const* d_in, const int* in_sizes, int n_in,
                              void* d_out, int out_size, void* d_ws, size_t ws_size,
                              hipStream_t stream) {
  const float* x     = (const float*)d_in[0];
  const float* mask  = (const float*)d_in[1];
  const float* rel   = (const float*)d_in[2];
  const float* qkvw  = (const float*)d_in[3];
  const float* qkvb  = (const float*)d_in[4];
  const float* projw = (const float*)d_in[5];
  const float* projb = (const float*)d_in[6];
  const float* fc1w  = (const float*)d_in[7];
  const float* fc1b  = (const float*)d_in[8];
  const float* fc2w  = (const float*)d_in[9];
  const float* fc2b  = (const float*)d_in[10];
  const float* tau   = (const float*)d_in[11];
  float* outp = (float*)d_out;
  char* ws = (char*)d_ws;

  float* norms  = (float*)(ws + OFF_NORM);
  float* slots  = (float*)(ws + OFF_SLOTS);
  f16*   wt     = (f16*)(ws + OFF_WT);
  f16*   pwt    = (f16*)(ws + OFF_PWT);
  f16*   biasp  = (f16*)(ws + OFF_BIASP);
  f16*   maskp  = (f16*)(ws + OFF_MASKP);
  f16*   qkv    = (f16*)(ws + OFF_QKV);

  (void)hipMemsetAsync(slots, 0, 512, stream);
  k_bias<<<256, 256, 0, stream>>>(rel, fc1w, fc1b, fc2w, fc2b, biasp);
  k_transpose<<<256, 256, 0, stream>>>(qkvw, projw, wt, pwt);
  k_perm<<<1024, 256, 0, stream>>>(mask, maskp);
  k_qkv<<<4096, 512, 0, stream>>>(x, wt, qkvb, qkv, slots);
  k_norm<<<1, 64, 0, stream>>>(slots, norms);
  k_attn<<<4096, 512, 0, stream>>>(qkv, qkv, biasp, maskp, norms, tau);
  k_proj<<<2048, 256, 0, stream>>>(qkv, pwt, projb, outp);
}

// Round 26
// 265.869 us; speedup vs baseline: 1.0150x; 1.0150x over previous
//
#include <hip/hip_runtime.h>
#include <hip/hip_fp16.h>
#include <cstddef>

typedef _Float16 f16;
typedef __attribute__((ext_vector_type(8))) _Float16 f16x8;
typedef __attribute__((ext_vector_type(4))) _Float16 f16x4;
typedef __attribute__((ext_vector_type(2))) _Float16 f16x2;
typedef __attribute__((ext_vector_type(4))) float f32x4;
typedef __attribute__((ext_vector_type(16))) float f32x16;
typedef __attribute__((ext_vector_type(4))) unsigned int u32x4;
typedef unsigned int u32;

#define LOG2E 1.44269504088896340736f

typedef __attribute__((address_space(1))) const unsigned int gau32;
typedef __attribute__((address_space(3))) unsigned int lau32;

// ---------------- workspace layout (bytes) ----------------
#define OFF_NORM  0ull                                // (unused; kept for layout stability)
#define OFF_SLOTS 128ull                              // 64 slot-pairs (spread atomics), 512 B
#define OFF_WT    1024ull                             // f16 wt2[12ct][8ks][32ln][2hi][8] (wave-coalesced)
#define OFF_PWT   (OFF_WT + 384ull*128*2)             // f16 pwt2[4ct][8ks][32ln][2hi][8] (wave-coalesced)
#define OFF_BIASP (OFF_PWT + 128ull*128*2)            // f16 bias2[4h][8g][8mt][32ln][2hi][16] (xLOG2E)
#define OFF_MASKP (OFF_BIASP + 4ull*256*256*2)        // f16 mask2[64w][8g][8mt][32ln][2hi][16] (xLOG2E)
#define OFF_QKV   (OFF_MASKP + 64ull*256*256*2)       // f16 q[1024][4][256][32] (-> overwritten by O), k same, vT[1024][4][32][256]
// end = OFF_QKV + 201,326,592 = 210,371,584 bytes (proven size)

#define QSZ 33554432ull   // elements per q/k/v section

// ---------------- K1: rel-pos bias MLP -> wave-coalesced f16 table (log2e-scaled) ----------------
__global__ void k_bias(const float* __restrict__ rel, const float* __restrict__ fc1w,
                       const float* __restrict__ fc1b, const float* __restrict__ fc2w,
                       const float* __restrict__ fc2b, f16* __restrict__ biasp) {
  int n = blockIdx.x, m = threadIdx.x;
  float r0 = rel[(n*256 + m)*2 + 0];
  float r1 = rel[(n*256 + m)*2 + 1];
  float a0 = fc2b[0], a1 = fc2b[1], a2 = fc2b[2], a3 = fc2b[3];
  for (int i = 0; i < 128; ++i) {
    float h = fmaf(r0, fc1w[i], fmaf(r1, fc1w[128 + i], fc1b[i]));
    float t = tanhf(0.7978845608028654f * (h + 0.044715f * h * h * h));
    float g = 0.5f * h * (1.0f + t);
    a0 = fmaf(g, fc2w[i*4 + 0], a0);
    a1 = fmaf(g, fc2w[i*4 + 1], a1);
    a2 = fmaf(g, fc2w[i*4 + 2], a2);
    a3 = fmaf(g, fc2w[i*4 + 3], a3);
  }
  int g = n >> 5, ln = n & 31;
  int mt = m >> 5, rem = m & 31;
  int rq = rem >> 3, hi = (rem >> 2) & 1, i = rem & 3;
  size_t base = (((size_t)(g*8 + mt)*32 + ln)*2 + hi)*16 + (rq*4 + i);
  biasp[0*65536 + base] = (f16)(a0 * LOG2E);
  biasp[1*65536 + base] = (f16)(a1 * LOG2E);
  biasp[2*65536 + base] = (f16)(a2 * LOG2E);
  biasp[3*65536 + base] = (f16)(a3 * LOG2E);
}

// ---------------- K2: weight transposes (fp32 -> fp16, both wave-coalesced) ----------------
__global__ void k_transpose(const float* __restrict__ qkvw, const float* __restrict__ projw,
                            f16* __restrict__ wt, f16* __restrict__ pwt) {
  int idx = blockIdx.x*256 + threadIdx.x;        // 0..65535
  if (idx < 49152) {
    int col = idx >> 7, k = idx & 127;
    int ct = col >> 5, ln = col & 31;
    int ks = k >> 4, hi = (k >> 3) & 1, j = k & 7;
    wt[(((size_t)(ct*8 + ks)*32 + ln)*2 + hi)*8 + j] = (f16)qkvw[k*384 + col];
  } else {
    int p = idx - 49152;
    int col = p >> 7, k = p & 127;
    int ct = col >> 5, ln = col & 31;
    int ks = k >> 4, hi = (k >> 3) & 1, j = k & 7;
    pwt[(((size_t)(ct*8 + ks)*32 + ln)*2 + hi)*8 + j] = (f16)projw[k*128 + col];
  }
}

// ---------------- K3: mask fp32 -> wave-coalesced f16 (log2e-scaled) ----------------
__global__ void k_perm(const float* __restrict__ mask, f16* __restrict__ maskp) {
  int t = blockIdx.x*256 + threadIdx.x;          // 0..262143
  int mt = t & 7, hi = (t >> 3) & 1, n = (t >> 4) & 255, w = t >> 12;
  int g = n >> 5, ln = n & 31;
  const float* src = mask + (size_t)(w*256 + n)*256;
  f16* dst = maskp + (size_t)w*65536 + (((size_t)(g*8 + mt)*32 + ln)*2 + hi)*16;
  #pragma unroll
  for (int rq = 0; rq < 4; ++rq) {
    f32x4 v = *(const f32x4*)(src + mt*32 + rq*8 + hi*4);
    #pragma unroll
    for (int i = 0; i < 4; ++i) dst[rq*4 + i] = (f16)(v[i] * LOG2E);
  }
}

// ---------------- K4: QKV GEMM (unchanged from r21) ----------------
__global__ __launch_bounds__(512, 6)
void k_qkv(const float* __restrict__ x, const f16* __restrict__ wt,
           const float* __restrict__ qkvb, f16* __restrict__ qkv,
           float* __restrict__ slots) {
  __shared__ f16 xs[8192];
  int tid = threadIdx.x;
  int wv = tid >> 6, lane = tid & 63;
  int ln = lane & 31, hi = lane >> 5;

  {
    const float* xt = x + (size_t)blockIdx.x*8192;
    char* xw = (char*)xs;
    #pragma unroll
    for (int it = 0; it < 4; ++it) {
      int idx = it*2048 + tid*4;
      int rowl = idx >> 7, col = idx & 127;
      f32x4 v = *(const f32x4*)(xt + idx);
      f16x4 hv;
      #pragma unroll
      for (int j = 0; j < 4; ++j) hv[j] = (f16)v[j];
      *(f16x4*)(xw + rowl*256 + ((col*2) ^ ((rowl & 15) << 4))) = hv;
    }
  }
  __syncthreads();

  int rl = (wv >> 2)*32 + ln;
  int row = blockIdx.x*64 + rl;
  int b_ = row >> 8, n = row & 255;
  int ct0 = (wv & 3)*3;

  f16x8 xf[8];
  {
    const char* xw = (const char*)xs;
    #pragma unroll
    for (int ks = 0; ks < 8; ++ks)
      xf[ks] = *(const f16x8*)(xw + rl*256 + ((ks*32 + hi*16) ^ ((rl & 15) << 4)));
  }
  __syncthreads();

  char* tb = (char*)xs + wv*2048;
  int nb0 = blockIdx.x*64 + (wv >> 2)*32;
  int b2 = nb0 >> 8, n2 = nb0 & 255;

  float sq = 0.f, sk = 0.f;
  #pragma unroll 1
  for (int cc = 0; cc < 3; ++cc) {
    int ct = ct0 + cc;
    f32x16 acc;
    #pragma unroll
    for (int g = 0; g < 4; ++g) {
      f32x4 qb = *(const f32x4*)(qkvb + ct*32 + g*8 + hi*4);
      #pragma unroll
      for (int i = 0; i < 4; ++i) acc[g*4 + i] = qb[i];
    }
    const f16* wbase = wt + (size_t)(ct*8)*512 + (ln*2 + hi)*8;
    #pragma unroll
    for (int ks = 0; ks < 8; ++ks) {
      f16x8 wf = *(const f16x8*)(wbase + ks*512);
      acc = __builtin_amdgcn_mfma_f32_32x32x16_f16(wf, xf[ks], acc, 0, 0, 0);
    }
    int which = ct >> 2, hh = ct & 3;
    if (which == 0) {
      #pragma unroll
      for (int r = 0; r < 16; ++r) sq = fmaf(acc[r], acc[r], sq);
    } else if (which == 1) {
      #pragma unroll
      for (int r = 0; r < 16; ++r) sk = fmaf(acc[r], acc[r], sk);
    }
    if (which < 2) {
      #pragma unroll
      for (int g = 0; g < 4; ++g) {
        f16x4 pk;
        #pragma unroll
        for (int i = 0; i < 4; ++i) pk[i] = (f16)acc[g*4 + i];
        *(f16x4*)(tb + g*512 + ln*16 + hi*8) = pk;
      }
      f16* dst0 = qkv + (size_t)which*QSZ + ((size_t)(b2*4 + hh)*256 + n2)*32;
      #pragma unroll
      for (int it = 0; it < 2; ++it) {
        int r = it*16 + (lane >> 2), u = lane & 3;
        f16x8 vv = *(const f16x8*)(tb + u*512 + r*16);
        *(f16x8*)((char*)dst0 + it*1024 + lane*16) = vv;
      }
    } else {
      f16* dst = qkv + 2ull*QSZ + ((size_t)(b_*4 + hh)*32)*256 + n;
      #pragma unroll
      for (int g = 0; g < 4; ++g) {
        #pragma unroll
        for (int i = 0; i < 4; ++i) {
          int dd = g*8 + hi*4 + i;
          dst[(size_t)dd*256] = (f16)acc[g*4 + i];
        }
      }
    }
  }
  #pragma unroll
  for (int o = 32; o > 0; o >>= 1) { sq += __shfl_xor(sq, o); sk += __shfl_xor(sk, o); }
  __syncthreads();
  float* red = (float*)xs;
  if (lane == 0) { red[wv*2] = sq; red[wv*2 + 1] = sk; }
  __syncthreads();
  if (tid == 0) {
    float a = 0.f, bsum = 0.f;
    #pragma unroll
    for (int i = 0; i < 8; ++i) { a += red[i*2]; bsum += red[i*2 + 1]; }
    float* sl = slots + 2*(blockIdx.x & 63);
    atomicAdd(sl + 0, a);
    atomicAdd(sl + 1, bsum);
  }
}

// ---------------- K5: window attention (r23 structure; norms reduced in-kernel from slots) ----------------
__global__ __launch_bounds__(512, 6)
void k_attn(const f16* __restrict__ qkv, f16* __restrict__ qo,
            const f16* __restrict__ biasp, const f16* __restrict__ maskp,
            const float* __restrict__ slots, const float* __restrict__ taup) {
  __shared__ f16 kbuf[8192];
  __shared__ f16 vbuf[8192];

  int blk = blockIdx.x;
  int xcd = blk & 7, s = blk >> 3;
  int b = (s >> 2)*8 + xcd;
  int h = s & 3;
  int w = b & 63;
  int tid = threadIdx.x;
  int wv = tid >> 6, lane = tid & 63;
  int ln = lane & 31, hi = lane >> 5;
  int n0 = wv * 32;
  int nrow = n0 + ln;

  // per-wave reduction of the 64 slot-pairs (L2-broadcast; replaces k_norm kernel)
  float nq = slots[2*lane], nk = slots[2*lane + 1];
  #pragma unroll
  for (int o = 32; o > 0; o >>= 1) { nq += __shfl_xor(nq, o); nk += __shfl_xor(nk, o); }

  float tau = fmaxf(taup[0], 0.01f);
  float scale = LOG2E / (sqrtf(nq) * sqrtf(nk) * tau);
  f16 scale_h = (f16)scale;
  f16x2 s2 = {scale_h, scale_h};

  const f16* qrow = qkv + (size_t)(b*4 + h)*8192 + (size_t)nrow*32 + hi*8;
  f16x8 qf0 = *(const f16x8*)(qrow);
  f16x8 qf1 = *(const f16x8*)(qrow + 16);

  {
    const char* kg = (const char*)(qkv + QSZ + (size_t)(b*4 + h)*8192);
    const char* vg = (const char*)(qkv + 2ull*QSZ + (size_t)(b*4 + h)*8192);
    #pragma unroll
    for (int it = 0; it < 2; ++it) {
      int t = it*512 + wv*64 + lane;
      int mt_ = t >> 7, ch = (t >> 5) & 3, l = t & 31;
      const char* src = kg + ((mt_*32 + l)*64 + ch*16);
      char* dst = (char*)kbuf + (size_t)(it*512 + wv*64)*16;
      __builtin_amdgcn_global_load_lds((gau32*)src, (lau32*)dst, 16, 0, 0);
    }
    #pragma unroll
    for (int it = 0; it < 2; ++it) {
      int t = it*512 + wv*64 + lane;
      int kc = t >> 5, dd = t & 31;
      const char* src = vg + (dd*512 + kc*16);
      char* dst = (char*)vbuf + (size_t)(it*512 + wv*64)*16;
      __builtin_amdgcn_global_load_lds((gau32*)src, (lau32*)dst, 16, 0, 0);
    }
  }
  __syncthreads();

  int g = wv;
  const u32* bp = (const u32*)biasp + (size_t)(h*8 + g)*4096 + (ln*2 + hi)*8;
  const u32* mp = (const u32*)maskp + (size_t)w*32768 + (size_t)g*4096 + (ln*2 + hi)*8;

  f32x16 oacc, sacc, zf;
  #pragma unroll
  for (int r = 0; r < 16; ++r) { oacc[r] = 0.f; sacc[r] = 0.f; zf[r] = 0.f; }
  f16x8 ones;
  #pragma unroll
  for (int j = 0; j < 8; ++j) ones[j] = (f16)1.0f;

  #pragma unroll 1
  for (int mt = 0; mt < 8; ++mt) {
    f16x8 ka0 = *(const f16x8*)(kbuf + ((size_t)((mt*4 + hi)*32 + ln))*8);
    f16x8 ka1 = *(const f16x8*)(kbuf + ((size_t)((mt*4 + 2 + hi)*32 + ln))*8);
    f32x16 c = __builtin_amdgcn_mfma_f32_32x32x16_f16(ka0, qf0, zf, 0, 0, 0);
    c = __builtin_amdgcn_mfma_f32_32x32x16_f16(ka1, qf1, c, 0, 0, 0);

    u32 u[8];
    #pragma unroll
    for (int j = 0; j < 8; ++j) {
      f16x2 bm = __builtin_bit_cast(f16x2, bp[j]) + __builtin_bit_cast(f16x2, mp[j]);
      f16x2 cp = __builtin_bit_cast(f16x2, __builtin_amdgcn_cvt_pkrtz(c[2*j], c[2*j + 1]));
      f16x2 l2 = cp * s2 + bm;
      __half2 e = h2exp2(__builtin_bit_cast(__half2, l2));
      u[j] = __builtin_bit_cast(u32, e);
    }
    bp += 512; mp += 512;
    #pragma unroll
    for (int half = 0; half < 2; ++half) {
      u32 q0 = u[half*4 + 0], q1 = u[half*4 + 1], q2 = u[half*4 + 2], q3 = u[half*4 + 3];
      asm volatile("v_permlane32_swap_b32 %0, %1" : "+v"(q0), "+v"(q2));
      asm volatile("v_permlane32_swap_b32 %0, %1" : "+v"(q1), "+v"(q3));
      u32x4 av; av[0] = q0; av[1] = q1; av[2] = q2; av[3] = q3;
      f16x8 afrag = __builtin_bit_cast(f16x8, av);
      int ks = mt*2 + half;
      f16x8 vfrag = *(const f16x8*)(vbuf + ((size_t)((2*ks + hi)*32 + ln))*8);
      oacc = __builtin_amdgcn_mfma_f32_32x32x16_f16(afrag, vfrag, oacc, 0, 0, 0);
      sacc = __builtin_amdgcn_mfma_f32_32x32x16_f16(afrag, ones, sacc, 0, 0, 0);
    }
  }

  f16* ob = qo + (size_t)(b*4 + h)*8192 + (size_t)n0*32 + ln;
  #pragma unroll
  for (int r = 0; r < 16; ++r) {
    int nl = (r & 3) + 8*(r >> 2) + 4*hi;
    float rcp = __builtin_amdgcn_rcpf(sacc[r]);
    ob[nl*32] = (f16)(oacc[r] * rcp);
  }
}

// ---------------- K6: proj GEMM with LDS-staged O (unchanged from r24) ----------------
__global__ __launch_bounds__(256, 4)
void k_proj(const f16* __restrict__ O, const f16* __restrict__ pwt,
            const float* __restrict__ projb, float* __restrict__ out) {
  __shared__ f16 os[16384];
  int blk = blockIdx.x;
  int xcd = blk & 7, s = blk >> 3;
  int window = (s >> 1)*8 + xcd;
  int half = s & 1;
  int tid = threadIdx.x;
  int wv = tid >> 6, lane = tid & 63;
  int ln = lane & 31, hi = lane >> 5;

  {
    const char* obase = (const char*)(O + ((size_t)window*4*256 + half*128)*32);
    char* ow = (char*)os;
    #pragma unroll
    for (int it = 0; it < 8; ++it) {
      int flat = it*4096 + tid*16;
      int h = flat >> 13;
      int rem = flat & 8191;
      int nloc = rem >> 6;
      int db = rem & 63;
      f16x8 v = *(const f16x8*)(obase + (size_t)h*16384 + nloc*64 + db);
      int cb = h*64 + db;
      *(f16x8*)(ow + nloc*256 + (cb ^ ((nloc & 15) << 4))) = v;
    }
  }
  __syncthreads();

  int rl = wv*32 + ln;
  int row0 = window*256 + half*128 + wv*32;

  f16x8 afr[8];
  {
    const char* ow = (const char*)os;
    #pragma unroll
    for (int ks = 0; ks < 8; ++ks)
      afr[ks] = *(const f16x8*)(ow + rl*256 + ((ks*32 + hi*16) ^ ((rl & 15) << 4)));
  }

  #pragma unroll 1
  for (int ct = 0; ct < 4; ++ct) {
    int cout = ct*32 + ln;
    float pb = projb[cout];
    f32x16 pacc;
    #pragma unroll
    for (int r = 0; r < 16; ++r) pacc[r] = pb;
    const f16* pbase = pwt + (size_t)(ct*8)*512 + (ln*2 + hi)*8;
    #pragma unroll
    for (int ks = 0; ks < 8; ++ks) {
      f16x8 bfr = *(const f16x8*)(pbase + ks*512);
      pacc = __builtin_amdgcn_mfma_f32_32x32x16_f16(afr[ks], bfr, pacc, 0, 0, 0);
    }
    #pragma unroll
    for (int r = 0; r < 16; ++r) {
      int nl = (r & 3) + 8*(r >> 2) + 4*hi;
      out[(size_t)(row0 + nl)*128 + cout] = pacc[r];
    }
  }
}

// ---------------- launch ----------------
extern "C" void kernel_launch(void* const* d_in, const int* in_sizes, int n_in,
                              void* d_out, int out_size, void* d_ws, size_t ws_size,
                              hipStream_t stream) {
  const float* x     = (const float*)d_in[0];
  const float* mask  = (const float*)d_in[1];
  const float* rel   = (const float*)d_in[2];
  const float* qkvw  = (const float*)d_in[3];
  const float* qkvb  = (const float*)d_in[4];
  const float* projw = (const float*)d_in[5];
  const float* projb = (const float*)d_in[6];
  const float* fc1w  = (const float*)d_in[7];
  const float* fc1b  = (const float*)d_in[8];
  const float* fc2w  = (const float*)d_in[9];
  const float* fc2b  = (const float*)d_in[10];
  const float* tau   = (const float*)d_in[11];
  float* outp = (float*)d_out;
  char* ws = (char*)d_ws;

  float* slots  = (float*)(ws + OFF_SLOTS);
  f16*   wt     = (f16*)(ws + OFF_WT);
  f16*   pwt    = (f16*)(ws + OFF_PWT);
  f16*   biasp  = (f16*)(ws + OFF_BIASP);
  f16*   maskp  = (f16*)(ws + OFF_MASKP);
  f16*   qkv    = (f16*)(ws + OFF_QKV);

  (void)hipMemsetAsync(slots, 0, 512, stream);
  k_bias<<<256, 256, 0, stream>>>(rel, fc1w, fc1b, fc2w, fc2b, biasp);
  k_transpose<<<256, 256, 0, stream>>>(qkvw, projw, wt, pwt);
  k_perm<<<1024, 256, 0, stream>>>(mask, maskp);
  k_qkv<<<4096, 512, 0, stream>>>(x, wt, qkvb, qkv, slots);
  k_attn<<<4096, 512, 0, stream>>>(qkv, qkv, biasp, maskp, slots, tau);
  k_proj<<<2048, 256, 0, stream>>>(qkv, pwt, projb, outp);
}